// Round 8
// baseline (309.038 us; speedup 1.0000x reference)
//
#include <hip/hip_runtime.h>
#include <hip/hip_fp16.h>

// Problem constants (fixed by the reference)
static constexpr int NN  = 50000;   // nodes (even, < 65536 so ids fit u16)
static constexpr int EE  = 800000;  // edges
static constexpr int CIN = 96;      // input channels
static constexpr int L1C = 70, S1 = 72;   // TAG layer 1 out (split: 64 main + 8 tail)
static constexpr int L2C = 43, S2P = 48;  // TAG layer 2 out (split: 32 main + 16 tail)

// ---- MFMA fragment-major weight images -------------------------------------
// Frag layout (v_mfma_f32_16x16x32_bf16, contiguous-k): lane l = idx + 16*(kloc/8)
// holds 8 bf16 at k = 32*s + 8*(l>>4) + [0..8); B operand col = l&15.
// Image = [tile t][kstep s][lane l] -> 16B frag, flat frag = (t*KS+s)*64 + l.
// GEMMs read B-frags DIRECTLY from these global images (wave-contiguous 1KB
// per frag = fully coalesced; image identical across blocks -> L2-resident).
static constexpr int NT1 = 18, KS1 = 3;   // GEMM1: N=288 (4 x 72), K=96
static constexpr int NT2 = 12, KS2 = 3;   // GEMM2: N=192 (4 x 48), K=72 (padded)
static constexpr int NTH = 2,  KSH = 2;   // GEMMH: N=32,          K=48 (padded)
static constexpr int NU1 = NT1 * KS1 * 64 * 4;  // uints = 13824
static constexpr int NU2 = NT2 * KS2 * 64 * 4;  // 9216
static constexpr int NUH = NTH * KSH * 64 * 4;  // 1024
static constexpr int TUW = NU1 + NU2 + NUH;     // 24064 uints
static constexpr int NBF = 288 + 192;           // bias floats (gemm1 + gemm2 cols)

static constexpr int NSLICE = 8;
static constexpr int SLICEN = NN / NSLICE;    // 6250

typedef short bf16x8 __attribute__((ext_vector_type(8)));  // 8 bf16 = 4 VGPRs
typedef float f32x4  __attribute__((ext_vector_type(4)));

// ------------------------------------------------------------ bf16 helpers
__device__ __forceinline__ float bf_lo(unsigned int u) {
    return __uint_as_float(u << 16);
}
__device__ __forceinline__ float bf_hi(unsigned int u) {
    return __uint_as_float(u & 0xffff0000u);
}
__device__ __forceinline__ unsigned int bf_rne_bits(float f) {
    unsigned int u = __float_as_uint(f);
    return u + 0x7fffu + ((u >> 16) & 1u);
}
__device__ __forceinline__ unsigned int pack_bf(float a, float b) {
    return (bf_rne_bits(a) >> 16) | (bf_rne_bits(b) & 0xffff0000u);
}
__device__ __forceinline__ void unpack_bf8(uint4 q, float* f) {
    f[0] = bf_lo(q.x); f[1] = bf_hi(q.x); f[2] = bf_lo(q.y); f[3] = bf_hi(q.y);
    f[4] = bf_lo(q.z); f[5] = bf_hi(q.z); f[6] = bf_lo(q.w); f[7] = bf_hi(q.w);
}

// edge record: src (low 16) | fp16 weight (high 16)
__device__ __forceinline__ int rec_src(unsigned int p) { return (int)(p & 0xffffu); }
__device__ __forceinline__ float rec_w(unsigned int p) {
    return __half2float(__ushort_as_half((unsigned short)(p >> 16)));
}

// ---------------------------------------------------------------- preprocessing

// Fused init: zero deg + repack weights into MFMA frag-major bf16 images
// + fp32 bias column vectors (bias only on image 0, zero elsewhere).
__global__ void init_kernel(const float* __restrict__ W1, const float* __restrict__ b1,
                            const float* __restrict__ W2, const float* __restrict__ b2,
                            const float* __restrict__ Wmu, const float* __restrict__ Wls,
                            unsigned int* __restrict__ wB, float* __restrict__ bB,
                            int* __restrict__ deg) {
    int i = blockIdx.x * blockDim.x + threadIdx.x;
    if (i < NN) deg[i] = 0;
    if (i < TUW) {
        float v0 = 0.f, v1 = 0.f;
        if (i < NU1) {
            int frag = i >> 2, j = i & 3;
            int l = frag & 63, ts = frag >> 6;
            int s = ts % 3, t = ts / 3;
            int col = t * 16 + (l & 15);          // 0..287
            int kb  = s * 32 + (l >> 4) * 8 + j * 2;  // even, <= 94
            int img = col / S1, cin = col - img * S1;
            if (cin < L1C) {
                const float* Wp = W1 + ((size_t)img * CIN + kb) * L1C + cin;
                v0 = Wp[0];        // k = kb   (always < 96)
                v1 = Wp[L1C];      // k = kb+1
            }
        } else if (i < NU1 + NU2) {
            int u = i - NU1;
            int frag = u >> 2, j = u & 3;
            int l = frag & 63, ts = frag >> 6;
            int s = ts % 3, t = ts / 3;
            int col = t * 16 + (l & 15);          // 0..191
            int kb  = s * 32 + (l >> 4) * 8 + j * 2;
            int img = col / S2P, cin = col - img * S2P;
            if (cin < L2C) {
                const float* Wp = W2 + ((size_t)img * L1C + kb) * L2C + cin;
                if (kb < L1C)     v0 = Wp[0];
                if (kb + 1 < L1C) v1 = Wp[L2C];
            }
        } else {
            int u = i - NU1 - NU2;
            int frag = u >> 2, j = u & 3;
            int l = frag & 63, ts = frag >> 6;
            int s = ts & 1, t = ts >> 1;
            int col = t * 16 + (l & 15);          // 0..31
            int kb  = s * 32 + (l >> 4) * 8 + j * 2;
            const float* Wsel = (col < 16) ? (Wmu + col) : (Wls + (col - 16));
            if (kb < L2C)     v0 = Wsel[kb * 16];
            if (kb + 1 < L2C) v1 = Wsel[(kb + 1) * 16];
        }
        wB[i] = pack_bf(v0, v1);
    } else if (i < TUW + NBF) {
        int j = i - TUW;
        float v = 0.f;
        if (j < 288) { if (j < L1C) v = b1[j]; }           // gemm1 cols (img0 only)
        else { int c = j - 288; if (c < L2C) v = b2[c]; }  // gemm2 cols
        bB[j] = v;
    }
}

// Histogram + rank capture: the atomicAdd's return IS each edge's rank within
// its destination bucket — store it packed with row so fill needs no atomics.
__global__ void hist_kernel(const int* __restrict__ row, const int* __restrict__ col,
                            int* __restrict__ deg, unsigned int* __restrict__ rr, int E) {
    int e = blockIdx.x * blockDim.x + threadIdx.x;
    if (e < E) {
        int c = col[e];
        int rk = atomicAdd(&deg[c], 1);
        rr[e] = ((unsigned int)rk << 16) | (unsigned int)row[e];
    }
}

static constexpr int SB = 256;  // scan block size

__global__ void reduce_kernel(const int* __restrict__ deg, int* __restrict__ bsum, int n) {
    __shared__ int sd[SB];
    int i = blockIdx.x * SB + threadIdx.x;
    sd[threadIdx.x] = (i < n) ? deg[i] : 0;
    __syncthreads();
    for (int s = SB / 2; s > 0; s >>= 1) {
        if (threadIdx.x < s) sd[threadIdx.x] += sd[threadIdx.x + s];
        __syncthreads();
    }
    if (threadIdx.x == 0) bsum[blockIdx.x] = sd[0];
}

// Fused block scan: each block computes its own bsum prefix, then the local
// exclusive scan; emits off/dis/dis2 (no cursor needed — fill is atomic-free).
__global__ void block_scan_kernel(const int* __restrict__ deg, const int* __restrict__ bsum,
                                  int* __restrict__ off,
                                  float* __restrict__ dis, float* __restrict__ dis2,
                                  int n, int nb) {
    __shared__ int sd[SB];
    __shared__ int bofs;
    int t = threadIdx.x;
    sd[t] = (t < nb && t < (int)blockIdx.x) ? bsum[t] : 0;
    __syncthreads();
    for (int s = SB / 2; s > 0; s >>= 1) {
        if (t < s) sd[t] += sd[t + s];
        __syncthreads();
    }
    if (t == 0) bofs = sd[0];
    __syncthreads();
    int i = blockIdx.x * SB + t;
    int v = (i < n) ? deg[i] : 0;
    sd[t] = v;
    __syncthreads();
    for (int s = 1; s < SB; s <<= 1) {
        int tv = (t >= s) ? sd[t - s] : 0;
        __syncthreads();
        sd[t] += tv;
        __syncthreads();
    }
    if (i < n) {
        int e = bofs + sd[t] - v;
        off[i] = e;
        dis[i]  = (v > 0) ? rsqrtf((float)v) : 0.0f;
        dis2[i] = rsqrtf((float)v + 1.0f);
        if (i == n - 1) off[n] = e + v;
    }
}

// Atomic-free destination-sliced fill: pos = off[c] + rank (rank captured in
// hist). Slicing kept for eTag write locality.
__global__ void fill_kernel(const int* __restrict__ col, const unsigned int* __restrict__ rr,
                            const float* __restrict__ dis, const int* __restrict__ off,
                            unsigned int* __restrict__ eTag, int E) {
    int s = blockIdx.x & (NSLICE - 1);
    int nlo = s * SLICEN, nhi = nlo + SLICEN;
    int stride = (gridDim.x >> 3) * blockDim.x;
    for (int e = (blockIdx.x >> 3) * blockDim.x + threadIdx.x; e < E; e += stride) {
        int c = col[e];
        if (c >= nlo && c < nhi) {
            unsigned int u = rr[e];
            int r = (int)(u & 0xffffu);
            int pos = off[c] + (int)(u >> 16);
            unsigned short h = __half_as_ushort(__float2half(dis[r] * dis[c]));
            eTag[pos] = (unsigned int)r | ((unsigned int)h << 16);
        }
    }
}

// ------------------------------------------------------------- aggregation (bf16)
// Wide-gather: thread = (node, 8-channel group) -> one uint4 (16B) per edge.
// SPLIT layout (MAINC > 0): main [N][MAINC] + tail [N][C-MAINC] at +N*MAINC.
template <int C, bool HASADD, bool RELU, int MAINC>
__global__ void aggw_kernel(const unsigned short* __restrict__ in, const unsigned short* addv,
                            unsigned short* out, const int* __restrict__ off,
                            const unsigned int* __restrict__ ep, int n) {
    constexpr int TPN = C / 8;  // threads per node (8 bf16 channels each)
    int t = blockIdx.x * blockDim.x + threadIdx.x;
    if (t >= n * TPN) return;
    int node = t / TPN;
    int cc = (t - node * TPN) * 8;
    // split addressing: row(idx) = base + boff + idx*nstride
    size_t boff;
    int nstride;
    if constexpr (MAINC > 0) {
        bool tail = (cc >= MAINC);
        boff = tail ? (size_t)n * MAINC + (cc - MAINC) : (size_t)cc;
        nstride = tail ? (C - MAINC) : MAINC;
    } else {
        boff = (size_t)cc;
        nstride = C;
    }
    int beg = off[node], end = off[node + 1];
    float a0[8], a1[8];
    #pragma unroll
    for (int j = 0; j < 8; ++j) { a0[j] = 0.f; a1[j] = 0.f; }

    auto scalar1 = [&](int e) {
        unsigned int p = ep[e];
        float w = rec_w(p);
        uint4 q = *reinterpret_cast<const uint4*>(in + boff + (size_t)rec_src(p) * nstride);
        float f[8];
        unpack_bf8(q, f);
        #pragma unroll
        for (int j = 0; j < 8; ++j) a0[j] += w * f[j];
    };
    auto quad = [&](uint4 P) {
        float w0 = rec_w(P.x), w1 = rec_w(P.y), w2 = rec_w(P.z), w3 = rec_w(P.w);
        uint4 q0 = *reinterpret_cast<const uint4*>(in + boff + (size_t)rec_src(P.x) * nstride);
        uint4 q1 = *reinterpret_cast<const uint4*>(in + boff + (size_t)rec_src(P.y) * nstride);
        uint4 q2 = *reinterpret_cast<const uint4*>(in + boff + (size_t)rec_src(P.z) * nstride);
        uint4 q3 = *reinterpret_cast<const uint4*>(in + boff + (size_t)rec_src(P.w) * nstride);
        float f[8];
        unpack_bf8(q0, f);
        #pragma unroll
        for (int j = 0; j < 8; ++j) a0[j] += w0 * f[j];
        unpack_bf8(q1, f);
        #pragma unroll
        for (int j = 0; j < 8; ++j) a1[j] += w1 * f[j];
        unpack_bf8(q2, f);
        #pragma unroll
        for (int j = 0; j < 8; ++j) a0[j] += w2 * f[j];
        unpack_bf8(q3, f);
        #pragma unroll
        for (int j = 0; j < 8; ++j) a1[j] += w3 * f[j];
    };

    int e = beg;
    for (; e < end && (e & 3); ++e) scalar1(e);   // align to 16B
    if (e + 4 <= end) {
        uint4 P = *reinterpret_cast<const uint4*>(ep + e);
        for (; e + 8 <= end; e += 4) {
            uint4 Pn = *reinterpret_cast<const uint4*>(ep + e + 4);  // prefetch
            quad(P);
            P = Pn;
        }
        quad(P);
        e += 4;
    }
    for (; e < end; ++e) scalar1(e);

    float r[8];
    #pragma unroll
    for (int j = 0; j < 8; ++j) r[j] = a0[j] + a1[j];
    if constexpr (HASADD) {
        uint4 qa = *reinterpret_cast<const uint4*>(addv + boff + (size_t)node * nstride);
        float f[8];
        unpack_bf8(qa, f);
        #pragma unroll
        for (int j = 0; j < 8; ++j) r[j] += f[j];
    }
    if constexpr (RELU) {
        #pragma unroll
        for (int j = 0; j < 8; ++j) r[j] = fmaxf(r[j], 0.f);
    }
    uint4 o;
    o.x = pack_bf(r[0], r[1]); o.y = pack_bf(r[2], r[3]);
    o.z = pack_bf(r[4], r[5]); o.w = pack_bf(r[6], r[7]);
    *reinterpret_cast<uint4*>(out + boff + (size_t)node * nstride) = o;
}

// GCN agg + self-loop + bias + split-store, fused final stage (R4 loop).
// yh rows are 64B line-aligned already — no split needed.
__global__ void agg_gcn_final_kernel(const unsigned short* __restrict__ yh,
                                     const int* __restrict__ off,
                                     const unsigned int* __restrict__ ep,
                                     const float* __restrict__ dis2,
                                     const float* __restrict__ bmu,
                                     const float* __restrict__ bls,
                                     float* __restrict__ outp, int n) {
    int t = blockIdx.x * blockDim.x + threadIdx.x;
    if (t >= n * 4) return;
    int node = t >> 2;
    int cc = (t & 3) * 8;
    int beg = off[node], end = off[node + 1];
    float a0[8], a1[8];
    #pragma unroll
    for (int j = 0; j < 8; ++j) { a0[j] = 0.f; a1[j] = 0.f; }

    auto scalar1 = [&](int e) {
        int s = rec_src(ep[e]);
        float w = dis2[s];
        uint4 q = *reinterpret_cast<const uint4*>(yh + (size_t)s * 32 + cc);
        float f[8];
        unpack_bf8(q, f);
        #pragma unroll
        for (int j = 0; j < 8; ++j) a0[j] += w * f[j];
    };
    auto quad = [&](uint4 P) {
        int s0 = rec_src(P.x), s1 = rec_src(P.y), s2 = rec_src(P.z), s3 = rec_src(P.w);
        float w0 = dis2[s0], w1 = dis2[s1], w2 = dis2[s2], w3 = dis2[s3];
        uint4 q0 = *reinterpret_cast<const uint4*>(yh + (size_t)s0 * 32 + cc);
        uint4 q1 = *reinterpret_cast<const uint4*>(yh + (size_t)s1 * 32 + cc);
        uint4 q2 = *reinterpret_cast<const uint4*>(yh + (size_t)s2 * 32 + cc);
        uint4 q3 = *reinterpret_cast<const uint4*>(yh + (size_t)s3 * 32 + cc);
        float f[8];
        unpack_bf8(q0, f);
        #pragma unroll
        for (int j = 0; j < 8; ++j) a0[j] += w0 * f[j];
        unpack_bf8(q1, f);
        #pragma unroll
        for (int j = 0; j < 8; ++j) a1[j] += w1 * f[j];
        unpack_bf8(q2, f);
        #pragma unroll
        for (int j = 0; j < 8; ++j) a0[j] += w2 * f[j];
        unpack_bf8(q3, f);
        #pragma unroll
        for (int j = 0; j < 8; ++j) a1[j] += w3 * f[j];
    };

    int e = beg;
    for (; e < end && (e & 3); ++e) scalar1(e);
    if (e + 4 <= end) {
        uint4 P = *reinterpret_cast<const uint4*>(ep + e);
        for (; e + 8 <= end; e += 4) {
            uint4 Pn = *reinterpret_cast<const uint4*>(ep + e + 4);
            quad(P);
            P = Pn;
        }
        quad(P);
        e += 4;
    }
    for (; e < end; ++e) scalar1(e);

    float d = dis2[node];
    uint4 qy = *reinterpret_cast<const uint4*>(yh + (size_t)node * 32 + cc);
    float yv[8];
    unpack_bf8(qy, yv);
    const float* bp = (cc < 16) ? (bmu + cc) : (bls + (cc - 16));
    float r[8];
    #pragma unroll
    for (int j = 0; j < 8; ++j)
        r[j] = d * (a0[j] + a1[j]) + d * d * yv[j] + bp[j];
    size_t o = (cc < 16) ? ((size_t)node * 16 + cc)
                         : ((size_t)n * 16 + (size_t)node * 16 + (cc - 16));
    *reinterpret_cast<float4*>(outp + o) = make_float4(r[0], r[1], r[2], r[3]);
    *reinterpret_cast<float4*>(outp + o + 4) = make_float4(r[4], r[5], r[6], r[7]);
}

// ----------------------------------------------------------------- MFMA GEMM
// Block = 256 threads = 4 independent waves (no LDS, no barrier).
// B-fragments read DIRECTLY from the frag-major global image: per frag a wave
// reads a contiguous 1KB segment (global_load_dwordx4, fully coalesced); the
// image is shared by all blocks -> L2-resident. R7's 55KB LDS staging capped
// occupancy at 2 blocks/CU (Occ 16%, MfmaUtil 4%) — the barrier + staging
// serialization was the cost, not the math.
// A-fragments per-lane in registers. CONV: fp32 input split hi/lo bf16
// (2x MFMA, fp32-accurate). SIM/SOM: split input/output layouts (see aggw).
template <int KS, int NT, int INS, int OIMG, bool CONV, bool BIAS, int SIM, int SOM>
__launch_bounds__(256, 3)
__global__ void gemm_kernel(const void* __restrict__ Xv,
                            const unsigned int* __restrict__ Wp,
                            const float* __restrict__ bv,
                            unsigned short* __restrict__ o0,
                            unsigned short* __restrict__ o1,
                            unsigned short* __restrict__ o2,
                            unsigned short* __restrict__ o3,
                            int n) {
    const int tid = threadIdx.x;
    const int mb = blockIdx.x * 64;
    const int w = tid >> 6, lane = tid & 63;
    const int ln = lane & 15, lg = lane >> 4;
    const int m = mb + w * 16 + ln;

    // A-fragments directly into registers
    bf16x8 ah[KS], al[KS];
    #pragma unroll
    for (int s = 0; s < KS; ++s) {
        int k0 = s * 32 + lg * 8;
        if constexpr (CONV) {
            bool ok = (m < n);
            const float4* xp = reinterpret_cast<const float4*>(
                (const float*)Xv + (size_t)m * INS + k0);
            float4 aa = ok ? xp[0] : make_float4(0.f, 0.f, 0.f, 0.f);
            float4 bb = ok ? xp[1] : make_float4(0.f, 0.f, 0.f, 0.f);
            float xv[8] = {aa.x, aa.y, aa.z, aa.w, bb.x, bb.y, bb.z, bb.w};
            unsigned int hb[4], lb[4];
            #pragma unroll
            for (int j = 0; j < 4; ++j) {
                float a0 = xv[2 * j], a1 = xv[2 * j + 1];
                unsigned int h0 = bf_rne_bits(a0) & 0xffff0000u;
                unsigned int h1 = bf_rne_bits(a1) & 0xffff0000u;
                float r0 = a0 - __uint_as_float(h0);
                float r1 = a1 - __uint_as_float(h1);
                hb[j] = (h0 >> 16) | h1;
                lb[j] = pack_bf(r0, r1);
            }
            uint4 qh = make_uint4(hb[0], hb[1], hb[2], hb[3]);
            uint4 ql = make_uint4(lb[0], lb[1], lb[2], lb[3]);
            ah[s] = *reinterpret_cast<bf16x8*>(&qh);
            al[s] = *reinterpret_cast<bf16x8*>(&ql);
        } else if constexpr (SIM > 0) {
            // split input: k0<SIM -> main [n][SIM]; k0<INS -> tail; else 0
            uint4 v = make_uint4(0u, 0u, 0u, 0u);
            const unsigned short* X = (const unsigned short*)Xv;
            if (m < n) {
                if (k0 < SIM)
                    v = *reinterpret_cast<const uint4*>(X + (size_t)m * SIM + k0);
                else if (k0 < INS)
                    v = *reinterpret_cast<const uint4*>(
                        X + (size_t)n * SIM + (size_t)m * (INS - SIM) + (k0 - SIM));
            }
            ah[s] = *reinterpret_cast<bf16x8*>(&v);
        } else {
            uint4 v = make_uint4(0u, 0u, 0u, 0u);
            if (m < n && k0 + 8 <= INS)
                v = *reinterpret_cast<const uint4*>(
                    (const unsigned short*)Xv + (size_t)m * INS + k0);
            ah[s] = *reinterpret_cast<bf16x8*>(&v);
        }
    }

    const bf16x8* Wf = reinterpret_cast<const bf16x8*>(Wp);  // global, L2-hot

    f32x4 acc[NT];
    #pragma unroll
    for (int t = 0; t < NT; ++t) {
        float b = 0.f;
        if constexpr (BIAS) b = bv[t * 16 + ln];
        acc[t] = (f32x4){b, b, b, b};
    }
    #pragma unroll
    for (int t = 0; t < NT; ++t) {
        #pragma unroll
        for (int s = 0; s < KS; ++s) {
            bf16x8 bw = Wf[(t * KS + s) * 64 + lane];
            acc[t] = __builtin_amdgcn_mfma_f32_16x16x32_bf16(ah[s], bw, acc[t], 0, 0, 0);
            if constexpr (CONV)
                acc[t] = __builtin_amdgcn_mfma_f32_16x16x32_bf16(al[s], bw, acc[t], 0, 0, 0);
        }
    }
    // Epilogue: D layout col = lane&15, row = 4*(lane>>4) + reg [verified].
    const int rbase = mb + w * 16 + lg * 4;
    #pragma unroll
    for (int t = 0; t < NT; ++t) {
        int c = t * 16 + ln;
        int img = c / OIMG;
        int colin = c - img * OIMG;
        unsigned short* ob = (img == 0) ? o0 : (img == 1) ? o1 : (img == 2) ? o2 : o3;
        #pragma unroll
        for (int r = 0; r < 4; ++r) {
            int mm = rbase + r;
            if (mm < n) {
                unsigned short v = (unsigned short)(bf_rne_bits(acc[t][r]) >> 16);
                if constexpr (SOM > 0) {
                    if (colin < SOM)
                        ob[(size_t)mm * SOM + colin] = v;
                    else
                        ob[(size_t)n * SOM + (size_t)mm * (OIMG - SOM) + (colin - SOM)] = v;
                } else {
                    ob[(size_t)mm * OIMG + colin] = v;
                }
            }
        }
    }
}

// ------------------------------------------------------------------ launch

extern "C" void kernel_launch(void* const* d_in, const int* in_sizes, int n_in,
                              void* d_out, int out_size, void* d_ws, size_t ws_size,
                              hipStream_t stream) {
    const float* x   = (const float*)d_in[0];
    const int*   ei  = (const int*)d_in[1];
    const float* W1  = (const float*)d_in[2];
    const float* b1  = (const float*)d_in[3];
    const float* W2  = (const float*)d_in[4];
    const float* b2  = (const float*)d_in[5];
    const float* Wmu = (const float*)d_in[6];
    const float* bmu = (const float*)d_in[7];
    const float* Wls = (const float*)d_in[8];
    const float* bls = (const float*)d_in[9];
    float* out = (float*)d_out;

    const int N = NN, E = EE;
    const int* row = ei;
    const int* col = ei + E;

    // workspace carve-up (256B aligned)
    char* p = (char*)d_ws;
    auto alloc = [&](size_t bytes) -> char* {
        char* r = p;
        p += (bytes + 255) & ~(size_t)255;
        return r;
    };
    int*   deg    = (int*)alloc((size_t)N * 4);
    int*   off    = (int*)alloc((size_t)(N + 1) * 4);
    int*   bsum   = (int*)alloc((size_t)256 * 4);
    float* dis    = (float*)alloc((size_t)N * 4);
    float* dis2   = (float*)alloc((size_t)N * 4);
    unsigned int* wB = (unsigned int*)alloc((size_t)TUW * 4);
    float* bB     = (float*)alloc((size_t)NBF * 4);
    unsigned int* eTag = (unsigned int*)alloc((size_t)E * 4);
    unsigned int* rr   = (unsigned int*)alloc((size_t)E * 4);
    unsigned short* y0 = (unsigned short*)alloc((size_t)N * S1 * 2);  // split 64+8
    unsigned short* y1 = (unsigned short*)alloc((size_t)N * S1 * 2);
    unsigned short* y2 = (unsigned short*)alloc((size_t)N * S1 * 2);
    unsigned short* y3 = (unsigned short*)alloc((size_t)N * S1 * 2);
    unsigned short* u0 = (unsigned short*)alloc((size_t)N * S2P * 2); // split 32+16
    unsigned short* u1 = (unsigned short*)alloc((size_t)N * S2P * 2);
    unsigned short* u2 = (unsigned short*)alloc((size_t)N * S2P * 2);
    unsigned short* u3 = (unsigned short*)alloc((size_t)N * S2P * 2);
    unsigned short* yh = (unsigned short*)alloc((size_t)N * 32 * 2);

    const unsigned int* W1b = wB;
    const unsigned int* W2b = wB + NU1;
    const unsigned int* Whb = wB + NU1 + NU2;
    const float* bv1 = bB;          // 288 cols
    const float* bv2 = bB + 288;    // 192 cols

    const int B = 256;
    int gE = (E + B - 1) / B;
    int nb = (N + SB - 1) / SB;  // 196 scan blocks

    // --- graph preprocessing -> CSR by destination (+ weight repack to bf16)
    init_kernel<<<nb, B, 0, stream>>>(W1, b1, W2, b2, Wmu, Wls, wB, bB, deg);
    hist_kernel<<<gE, B, 0, stream>>>(row, col, deg, rr, E);
    reduce_kernel<<<nb, SB, 0, stream>>>(deg, bsum, N);
    block_scan_kernel<<<nb, SB, 0, stream>>>(deg, bsum, off, dis, dis2, N, nb);
    fill_kernel<<<3200, B, 0, stream>>>(col, rr, dis, off, eTag, E);

    // grids
    int gmm  = (N + 63) / 64;                     // 782 GEMM blocks
    int ga72 = (N * (S1 / 8) + B - 1) / B;        // TPN 9
    int ga48 = (N * (S2P / 8) + B - 1) / B;       // TPN 6
    int gaF  = (N * 4 + B - 1) / B;               // TPN 4

    // --- TAG layer 1 via Horner: o1 = relu(y0 + A(y1 + A(y2 + A*y3)))
    gemm_kernel<3, 18, CIN, S1, true, true, 0, 64><<<gmm, B, 0, stream>>>(
        x, W1b, bv1, y0, y1, y2, y3, N);
    aggw_kernel<S1, true, false, 64><<<ga72, B, 0, stream>>>(y3, y2, y2, off, eTag, N);
    aggw_kernel<S1, true, false, 64><<<ga72, B, 0, stream>>>(y2, y1, y1, off, eTag, N);
    aggw_kernel<S1, true, true , 64><<<ga72, B, 0, stream>>>(y1, y0, y0, off, eTag, N);
    // o1 = y0 (bf16, split layout, pad cols zero)

    // --- TAG layer 2 via Horner: o2 = relu(u0 + A(u1 + A(u2 + A*u3)))
    gemm_kernel<3, 12, S1, S2P, false, true, 64, 32><<<gmm, B, 0, stream>>>(
        y0, W2b, bv2, u0, u1, u2, u3, N);
    aggw_kernel<S2P, true, false, 32><<<ga48, B, 0, stream>>>(u3, u2, u2, off, eTag, N);
    aggw_kernel<S2P, true, false, 32><<<ga48, B, 0, stream>>>(u2, u1, u1, off, eTag, N);
    aggw_kernel<S2P, true, true , 32><<<ga48, B, 0, stream>>>(u1, u0, u0, off, eTag, N);
    // o2 = u0 (bf16, split layout, pad cols zero)

    // --- GCN heads: MFMA head matmul (48 -> 32), then fused final agg
    gemm_kernel<2, 2, S2P, 32, false, false, 32, 0><<<gmm, B, 0, stream>>>(
        u0, Whb, nullptr, yh, yh, yh, yh, N);
    agg_gcn_final_kernel<<<gaF, B, 0, stream>>>(yh, off, eTag, dis2, bmu, bls, out, N);
}

// Round 9
// 302.393 us; speedup vs baseline: 1.0220x; 1.0220x over previous
//
#include <hip/hip_runtime.h>
#include <hip/hip_fp16.h>

// Problem constants (fixed by the reference)
static constexpr int NN  = 50000;   // nodes (even, < 65536 so ids fit u16)
static constexpr int EE  = 800000;  // edges
static constexpr int CIN = 96;      // input channels
static constexpr int L1C = 70, S1 = 72;   // TAG layer 1 out (split: 64 main + 8 tail)
static constexpr int L2C = 43, S2P = 48;  // TAG layer 2 out, padded stride (6x16B)

// ---- MFMA fragment-major weight images -------------------------------------
// Frag layout (v_mfma_f32_16x16x32_bf16, contiguous-k): lane l = idx + 16*(kloc/8)
// holds 8 bf16 at k = 32*s + 8*(l>>4) + [0..8); B operand col = l&15.
// Image = [tile t][kstep s][lane l] -> 16B frag, flat frag = (t*KS+s)*64 + l.
static constexpr int NT1 = 18, KS1 = 3;   // GEMM1: N=288 (4 x 72), K=96
static constexpr int NT2 = 12, KS2 = 3;   // GEMM2: N=192 (4 x 48), K=72 (padded)
static constexpr int NTH = 2,  KSH = 2;   // GEMMH: N=32,          K=48 (padded)
static constexpr int NU1 = NT1 * KS1 * 64 * 4;  // uints = 13824
static constexpr int NU2 = NT2 * KS2 * 64 * 4;  // 9216
static constexpr int NUH = NTH * KSH * 64 * 4;  // 1024
static constexpr int TUW = NU1 + NU2 + NUH;     // 24064 uints
static constexpr int NBF = 288 + 192;           // bias floats (gemm1 + gemm2 cols)

static constexpr int NSLICE = 8;
static constexpr int SLICEN = NN / NSLICE;    // 6250

typedef short bf16x8 __attribute__((ext_vector_type(8)));  // 8 bf16 = 4 VGPRs
typedef float f32x4  __attribute__((ext_vector_type(4)));

// ------------------------------------------------------------ bf16 helpers
__device__ __forceinline__ float bf_lo(unsigned int u) {
    return __uint_as_float(u << 16);
}
__device__ __forceinline__ float bf_hi(unsigned int u) {
    return __uint_as_float(u & 0xffff0000u);
}
__device__ __forceinline__ unsigned int bf_rne_bits(float f) {
    unsigned int u = __float_as_uint(f);
    return u + 0x7fffu + ((u >> 16) & 1u);
}
__device__ __forceinline__ unsigned int pack_bf(float a, float b) {
    return (bf_rne_bits(a) >> 16) | (bf_rne_bits(b) & 0xffff0000u);
}
__device__ __forceinline__ void unpack_bf8(uint4 q, float* f) {
    f[0] = bf_lo(q.x); f[1] = bf_hi(q.x); f[2] = bf_lo(q.y); f[3] = bf_hi(q.y);
    f[4] = bf_lo(q.z); f[5] = bf_hi(q.z); f[6] = bf_lo(q.w); f[7] = bf_hi(q.w);
}

// edge record: src (low 16) | fp16 weight (high 16)
__device__ __forceinline__ int rec_src(unsigned int p) { return (int)(p & 0xffffu); }
__device__ __forceinline__ float rec_w(unsigned int p) {
    return __half2float(__ushort_as_half((unsigned short)(p >> 16)));
}

// ---------------------------------------------------------------- preprocessing

// Fused init: zero deg + repack weights into MFMA frag-major bf16 images
// + fp32 bias column vectors (bias only on image 0, zero elsewhere).
__global__ void init_kernel(const float* __restrict__ W1, const float* __restrict__ b1,
                            const float* __restrict__ W2, const float* __restrict__ b2,
                            const float* __restrict__ Wmu, const float* __restrict__ Wls,
                            unsigned int* __restrict__ wB, float* __restrict__ bB,
                            int* __restrict__ deg) {
    int i = blockIdx.x * blockDim.x + threadIdx.x;
    if (i < NN) deg[i] = 0;
    if (i < TUW) {
        float v0 = 0.f, v1 = 0.f;
        if (i < NU1) {
            int frag = i >> 2, j = i & 3;
            int l = frag & 63, ts = frag >> 6;
            int s = ts % 3, t = ts / 3;
            int col = t * 16 + (l & 15);          // 0..287
            int kb  = s * 32 + (l >> 4) * 8 + j * 2;  // even, <= 94
            int img = col / S1, cin = col - img * S1;
            if (cin < L1C) {
                const float* Wp = W1 + ((size_t)img * CIN + kb) * L1C + cin;
                v0 = Wp[0];        // k = kb   (always < 96)
                v1 = Wp[L1C];      // k = kb+1
            }
        } else if (i < NU1 + NU2) {
            int u = i - NU1;
            int frag = u >> 2, j = u & 3;
            int l = frag & 63, ts = frag >> 6;
            int s = ts % 3, t = ts / 3;
            int col = t * 16 + (l & 15);          // 0..191
            int kb  = s * 32 + (l >> 4) * 8 + j * 2;
            int img = col / S2P, cin = col - img * S2P;
            if (cin < L2C) {
                const float* Wp = W2 + ((size_t)img * L1C + kb) * L2C + cin;
                if (kb < L1C)     v0 = Wp[0];
                if (kb + 1 < L1C) v1 = Wp[L2C];
            }
        } else {
            int u = i - NU1 - NU2;
            int frag = u >> 2, j = u & 3;
            int l = frag & 63, ts = frag >> 6;
            int s = ts & 1, t = ts >> 1;
            int col = t * 16 + (l & 15);          // 0..31
            int kb  = s * 32 + (l >> 4) * 8 + j * 2;
            const float* Wsel = (col < 16) ? (Wmu + col) : (Wls + (col - 16));
            if (kb < L2C)     v0 = Wsel[kb * 16];
            if (kb + 1 < L2C) v1 = Wsel[(kb + 1) * 16];
        }
        wB[i] = pack_bf(v0, v1);
    } else if (i < TUW + NBF) {
        int j = i - TUW;
        float v = 0.f;
        if (j < 288) { if (j < L1C) v = b1[j]; }           // gemm1 cols (img0 only)
        else { int c = j - 288; if (c < L2C) v = b2[c]; }  // gemm2 cols
        bB[j] = v;
    }
}

// Histogram + rank capture: the atomicAdd's return IS each edge's rank within
// its destination bucket — store it packed with row so fill needs no atomics.
__global__ void hist_kernel(const int* __restrict__ row, const int* __restrict__ col,
                            int* __restrict__ deg, unsigned int* __restrict__ rr, int E) {
    int e = blockIdx.x * blockDim.x + threadIdx.x;
    if (e < E) {
        int c = col[e];
        int rk = atomicAdd(&deg[c], 1);
        rr[e] = ((unsigned int)rk << 16) | (unsigned int)row[e];
    }
}

static constexpr int SB = 256;  // scan block size

__global__ void reduce_kernel(const int* __restrict__ deg, int* __restrict__ bsum, int n) {
    __shared__ int sd[SB];
    int i = blockIdx.x * SB + threadIdx.x;
    sd[threadIdx.x] = (i < n) ? deg[i] : 0;
    __syncthreads();
    for (int s = SB / 2; s > 0; s >>= 1) {
        if (threadIdx.x < s) sd[threadIdx.x] += sd[threadIdx.x + s];
        __syncthreads();
    }
    if (threadIdx.x == 0) bsum[blockIdx.x] = sd[0];
}

// Fused block scan: each block computes its own bsum prefix, then the local
// exclusive scan; emits off/dis/dis2 (no cursor needed — fill is atomic-free).
__global__ void block_scan_kernel(const int* __restrict__ deg, const int* __restrict__ bsum,
                                  int* __restrict__ off,
                                  float* __restrict__ dis, float* __restrict__ dis2,
                                  int n, int nb) {
    __shared__ int sd[SB];
    __shared__ int bofs;
    int t = threadIdx.x;
    sd[t] = (t < nb && t < (int)blockIdx.x) ? bsum[t] : 0;
    __syncthreads();
    for (int s = SB / 2; s > 0; s >>= 1) {
        if (t < s) sd[t] += sd[t + s];
        __syncthreads();
    }
    if (t == 0) bofs = sd[0];
    __syncthreads();
    int i = blockIdx.x * SB + t;
    int v = (i < n) ? deg[i] : 0;
    sd[t] = v;
    __syncthreads();
    for (int s = 1; s < SB; s <<= 1) {
        int tv = (t >= s) ? sd[t - s] : 0;
        __syncthreads();
        sd[t] += tv;
        __syncthreads();
    }
    if (i < n) {
        int e = bofs + sd[t] - v;
        off[i] = e;
        dis[i]  = (v > 0) ? rsqrtf((float)v) : 0.0f;
        dis2[i] = rsqrtf((float)v + 1.0f);
        if (i == n - 1) off[n] = e + v;
    }
}

// Atomic-free destination-sliced fill: pos = off[c] + rank (rank captured in
// hist). Slicing kept for eTag write locality.
__global__ void fill_kernel(const int* __restrict__ col, const unsigned int* __restrict__ rr,
                            const float* __restrict__ dis, const int* __restrict__ off,
                            unsigned int* __restrict__ eTag, int E) {
    int s = blockIdx.x & (NSLICE - 1);
    int nlo = s * SLICEN, nhi = nlo + SLICEN;
    int stride = (gridDim.x >> 3) * blockDim.x;
    for (int e = (blockIdx.x >> 3) * blockDim.x + threadIdx.x; e < E; e += stride) {
        int c = col[e];
        if (c >= nlo && c < nhi) {
            unsigned int u = rr[e];
            int r = (int)(u & 0xffffu);
            int pos = off[c] + (int)(u >> 16);
            unsigned short h = __half_as_ushort(__float2half(dis[r] * dis[c]));
            eTag[pos] = (unsigned int)r | ((unsigned int)h << 16);
        }
    }
}

// ------------------------------------------------------------- aggregation (bf16)
// Wide-gather: thread = (node, 8-channel group) -> one uint4 (16B) per edge.
// SPLIT layout (layer 1, 72 ch): main [N][64] (128B rows, line-aligned) + tail
// [N][8] at base + N*64 (800KB, stays hot in L2). Layer 2 stays contiguous
// (R7 measured the 32+16 split as a small regression — TPN threads of a node
// read the same row in-wave, so line over-fetch was already amortized).
template <int C, bool HASADD, bool RELU, bool SPLIT>
__global__ void aggw_kernel(const unsigned short* __restrict__ in, const unsigned short* addv,
                            unsigned short* out, const int* __restrict__ off,
                            const unsigned int* __restrict__ ep, int n) {
    constexpr int TPN = C / 8;  // threads per node (8 bf16 channels each)
    int t = blockIdx.x * blockDim.x + threadIdx.x;
    if (t >= n * TPN) return;
    int node = t / TPN;
    int cc = (t - node * TPN) * 8;
    // split addressing: row(idx) = base + boff + idx*nstride
    size_t boff;
    int nstride;
    if constexpr (SPLIT) {
        bool tail = (cc == 64);
        boff = tail ? (size_t)n * 64 : (size_t)cc;
        nstride = tail ? 8 : 64;
    } else {
        boff = (size_t)cc;
        nstride = C;
    }
    int beg = off[node], end = off[node + 1];
    float a0[8], a1[8];
    #pragma unroll
    for (int j = 0; j < 8; ++j) { a0[j] = 0.f; a1[j] = 0.f; }

    auto scalar1 = [&](int e) {
        unsigned int p = ep[e];
        float w = rec_w(p);
        uint4 q = *reinterpret_cast<const uint4*>(in + boff + (size_t)rec_src(p) * nstride);
        float f[8];
        unpack_bf8(q, f);
        #pragma unroll
        for (int j = 0; j < 8; ++j) a0[j] += w * f[j];
    };
    auto quad = [&](uint4 P) {
        float w0 = rec_w(P.x), w1 = rec_w(P.y), w2 = rec_w(P.z), w3 = rec_w(P.w);
        uint4 q0 = *reinterpret_cast<const uint4*>(in + boff + (size_t)rec_src(P.x) * nstride);
        uint4 q1 = *reinterpret_cast<const uint4*>(in + boff + (size_t)rec_src(P.y) * nstride);
        uint4 q2 = *reinterpret_cast<const uint4*>(in + boff + (size_t)rec_src(P.z) * nstride);
        uint4 q3 = *reinterpret_cast<const uint4*>(in + boff + (size_t)rec_src(P.w) * nstride);
        float f[8];
        unpack_bf8(q0, f);
        #pragma unroll
        for (int j = 0; j < 8; ++j) a0[j] += w0 * f[j];
        unpack_bf8(q1, f);
        #pragma unroll
        for (int j = 0; j < 8; ++j) a1[j] += w1 * f[j];
        unpack_bf8(q2, f);
        #pragma unroll
        for (int j = 0; j < 8; ++j) a0[j] += w2 * f[j];
        unpack_bf8(q3, f);
        #pragma unroll
        for (int j = 0; j < 8; ++j) a1[j] += w3 * f[j];
    };

    int e = beg;
    for (; e < end && (e & 3); ++e) scalar1(e);   // align to 16B
    if (e + 4 <= end) {
        uint4 P = *reinterpret_cast<const uint4*>(ep + e);
        for (; e + 8 <= end; e += 4) {
            uint4 Pn = *reinterpret_cast<const uint4*>(ep + e + 4);  // prefetch
            quad(P);
            P = Pn;
        }
        quad(P);
        e += 4;
    }
    for (; e < end; ++e) scalar1(e);

    float r[8];
    #pragma unroll
    for (int j = 0; j < 8; ++j) r[j] = a0[j] + a1[j];
    if constexpr (HASADD) {
        uint4 qa = *reinterpret_cast<const uint4*>(addv + boff + (size_t)node * nstride);
        float f[8];
        unpack_bf8(qa, f);
        #pragma unroll
        for (int j = 0; j < 8; ++j) r[j] += f[j];
    }
    if constexpr (RELU) {
        #pragma unroll
        for (int j = 0; j < 8; ++j) r[j] = fmaxf(r[j], 0.f);
    }
    uint4 o;
    o.x = pack_bf(r[0], r[1]); o.y = pack_bf(r[2], r[3]);
    o.z = pack_bf(r[4], r[5]); o.w = pack_bf(r[6], r[7]);
    *reinterpret_cast<uint4*>(out + boff + (size_t)node * nstride) = o;
}

// GCN agg + self-loop + bias + split-store, fused final stage.
__global__ void agg_gcn_final_kernel(const unsigned short* __restrict__ yh,
                                     const int* __restrict__ off,
                                     const unsigned int* __restrict__ ep,
                                     const float* __restrict__ dis2,
                                     const float* __restrict__ bmu,
                                     const float* __restrict__ bls,
                                     float* __restrict__ outp, int n) {
    int t = blockIdx.x * blockDim.x + threadIdx.x;
    if (t >= n * 4) return;
    int node = t >> 2;
    int cc = (t & 3) * 8;
    int beg = off[node], end = off[node + 1];
    float a0[8], a1[8];
    #pragma unroll
    for (int j = 0; j < 8; ++j) { a0[j] = 0.f; a1[j] = 0.f; }

    auto scalar1 = [&](int e) {
        int s = rec_src(ep[e]);
        float w = dis2[s];
        uint4 q = *reinterpret_cast<const uint4*>(yh + (size_t)s * 32 + cc);
        float f[8];
        unpack_bf8(q, f);
        #pragma unroll
        for (int j = 0; j < 8; ++j) a0[j] += w * f[j];
    };
    auto quad = [&](uint4 P) {
        int s0 = rec_src(P.x), s1 = rec_src(P.y), s2 = rec_src(P.z), s3 = rec_src(P.w);
        float w0 = dis2[s0], w1 = dis2[s1], w2 = dis2[s2], w3 = dis2[s3];
        uint4 q0 = *reinterpret_cast<const uint4*>(yh + (size_t)s0 * 32 + cc);
        uint4 q1 = *reinterpret_cast<const uint4*>(yh + (size_t)s1 * 32 + cc);
        uint4 q2 = *reinterpret_cast<const uint4*>(yh + (size_t)s2 * 32 + cc);
        uint4 q3 = *reinterpret_cast<const uint4*>(yh + (size_t)s3 * 32 + cc);
        float f[8];
        unpack_bf8(q0, f);
        #pragma unroll
        for (int j = 0; j < 8; ++j) a0[j] += w0 * f[j];
        unpack_bf8(q1, f);
        #pragma unroll
        for (int j = 0; j < 8; ++j) a1[j] += w1 * f[j];
        unpack_bf8(q2, f);
        #pragma unroll
        for (int j = 0; j < 8; ++j) a0[j] += w2 * f[j];
        unpack_bf8(q3, f);
        #pragma unroll
        for (int j = 0; j < 8; ++j) a1[j] += w3 * f[j];
    };

    int e = beg;
    for (; e < end && (e & 3); ++e) scalar1(e);
    if (e + 4 <= end) {
        uint4 P = *reinterpret_cast<const uint4*>(ep + e);
        for (; e + 8 <= end; e += 4) {
            uint4 Pn = *reinterpret_cast<const uint4*>(ep + e + 4);
            quad(P);
            P = Pn;
        }
        quad(P);
        e += 4;
    }
    for (; e < end; ++e) scalar1(e);

    float d = dis2[node];
    uint4 qy = *reinterpret_cast<const uint4*>(yh + (size_t)node * 32 + cc);
    float yv[8];
    unpack_bf8(qy, yv);
    const float* bp = (cc < 16) ? (bmu + cc) : (bls + (cc - 16));
    float r[8];
    #pragma unroll
    for (int j = 0; j < 8; ++j)
        r[j] = d * (a0[j] + a1[j]) + d * d * yv[j] + bp[j];
    size_t o = (cc < 16) ? ((size_t)node * 16 + cc)
                         : ((size_t)n * 16 + (size_t)node * 16 + (cc - 16));
    *reinterpret_cast<float4*>(outp + o) = make_float4(r[0], r[1], r[2], r[3]);
    *reinterpret_cast<float4*>(outp + o + 4) = make_float4(r[4], r[5], r[6], r[7]);
}

// ----------------------------------------------------------------- MFMA GEMM
// Block = 256 threads = 4 waves, BM = 64 rows (wave w owns rows mb+16w..+15).
// Weights staged frag-major in LDS; A-fragments per-lane in registers.
// (R8's no-LDS variant measured null vs this — keeping the R6 best-measured
// form.) CONV: fp32 input split hi/lo bf16 (2x MFMA, fp32-accurate).
// SIN : A input in split layout (main [n][64] + tail [n][8] at +n*64).
// SOUT: outputs in split layout (used by layer-1 images, OIMG=72).
template <int KS, int NT, int INS, int OIMG, bool CONV, bool BIAS, bool SIN, bool SOUT>
__launch_bounds__(256)
__global__ void gemm_kernel(const void* __restrict__ Xv,
                            const unsigned int* __restrict__ Wp,
                            const float* __restrict__ bv,
                            unsigned short* __restrict__ o0,
                            unsigned short* __restrict__ o1,
                            unsigned short* __restrict__ o2,
                            unsigned short* __restrict__ o3,
                            int n) {
    constexpr int WFR = NT * KS * 64;   // weight frags (16B each)
    __shared__ __align__(16) unsigned int Wl[WFR * 4];

    const int tid = threadIdx.x;
    const int mb = blockIdx.x * 64;

    {   // stage weights (already frag-major in global)
        const uint4* s4 = reinterpret_cast<const uint4*>(Wp);
        uint4* d4 = reinterpret_cast<uint4*>(Wl);
        for (int i = tid; i < WFR; i += 256) d4[i] = s4[i];
    }

    const int w = tid >> 6, lane = tid & 63;
    const int ln = lane & 15, lg = lane >> 4;
    const int m = mb + w * 16 + ln;

    // A-fragments directly into registers
    bf16x8 ah[KS], al[KS];
    #pragma unroll
    for (int s = 0; s < KS; ++s) {
        int k0 = s * 32 + lg * 8;
        if constexpr (CONV) {
            bool ok = (m < n);
            const float4* xp = reinterpret_cast<const float4*>(
                (const float*)Xv + (size_t)m * INS + k0);
            float4 aa = ok ? xp[0] : make_float4(0.f, 0.f, 0.f, 0.f);
            float4 bb = ok ? xp[1] : make_float4(0.f, 0.f, 0.f, 0.f);
            float xv[8] = {aa.x, aa.y, aa.z, aa.w, bb.x, bb.y, bb.z, bb.w};
            unsigned int hb[4], lb[4];
            #pragma unroll
            for (int j = 0; j < 4; ++j) {
                float a0 = xv[2 * j], a1 = xv[2 * j + 1];
                unsigned int h0 = bf_rne_bits(a0) & 0xffff0000u;
                unsigned int h1 = bf_rne_bits(a1) & 0xffff0000u;
                float r0 = a0 - __uint_as_float(h0);
                float r1 = a1 - __uint_as_float(h1);
                hb[j] = (h0 >> 16) | h1;
                lb[j] = pack_bf(r0, r1);
            }
            uint4 qh = make_uint4(hb[0], hb[1], hb[2], hb[3]);
            uint4 ql = make_uint4(lb[0], lb[1], lb[2], lb[3]);
            ah[s] = *reinterpret_cast<bf16x8*>(&qh);
            al[s] = *reinterpret_cast<bf16x8*>(&ql);
        } else if constexpr (SIN) {
            // split input: k0<64 -> main [n][64]; k0==64 -> tail; k0>=72 -> 0
            uint4 v = make_uint4(0u, 0u, 0u, 0u);
            const unsigned short* X = (const unsigned short*)Xv;
            if (m < n) {
                if (k0 < 64)
                    v = *reinterpret_cast<const uint4*>(X + (size_t)m * 64 + k0);
                else if (k0 == 64)
                    v = *reinterpret_cast<const uint4*>(X + (size_t)n * 64 + (size_t)m * 8);
            }
            ah[s] = *reinterpret_cast<bf16x8*>(&v);
        } else {
            uint4 v = make_uint4(0u, 0u, 0u, 0u);
            if (m < n && k0 + 8 <= INS)
                v = *reinterpret_cast<const uint4*>(
                    (const unsigned short*)Xv + (size_t)m * INS + k0);
            ah[s] = *reinterpret_cast<bf16x8*>(&v);
        }
    }
    __syncthreads();  // weights staged

    const bf16x8* Wf = reinterpret_cast<const bf16x8*>(Wl);

    f32x4 acc[NT];
    #pragma unroll
    for (int t = 0; t < NT; ++t) {
        float b = 0.f;
        if constexpr (BIAS) b = bv[t * 16 + ln];
        acc[t] = (f32x4){b, b, b, b};
    }
    #pragma unroll
    for (int s = 0; s < KS; ++s) {
        #pragma unroll
        for (int t = 0; t < NT; ++t) {
            bf16x8 bw = Wf[(t * KS + s) * 64 + lane];
            acc[t] = __builtin_amdgcn_mfma_f32_16x16x32_bf16(ah[s], bw, acc[t], 0, 0, 0);
            if constexpr (CONV)
                acc[t] = __builtin_amdgcn_mfma_f32_16x16x32_bf16(al[s], bw, acc[t], 0, 0, 0);
        }
    }
    // Epilogue: D layout col = lane&15, row = 4*(lane>>4) + reg [verified].
    const int rbase = mb + w * 16 + lg * 4;
    #pragma unroll
    for (int t = 0; t < NT; ++t) {
        int c = t * 16 + ln;
        int img = c / OIMG;
        int colin = c - img * OIMG;
        unsigned short* ob = (img == 0) ? o0 : (img == 1) ? o1 : (img == 2) ? o2 : o3;
        #pragma unroll
        for (int r = 0; r < 4; ++r) {
            int mm = rbase + r;
            if (mm < n) {
                unsigned short v = (unsigned short)(bf_rne_bits(acc[t][r]) >> 16);
                if constexpr (SOUT) {
                    if (colin < 64)
                        ob[(size_t)mm * 64 + colin] = v;
                    else
                        ob[(size_t)n * 64 + (size_t)mm * 8 + (colin - 64)] = v;
                } else {
                    ob[(size_t)mm * OIMG + colin] = v;
                }
            }
        }
    }
}

// ------------------------------------------------------------------ launch

extern "C" void kernel_launch(void* const* d_in, const int* in_sizes, int n_in,
                              void* d_out, int out_size, void* d_ws, size_t ws_size,
                              hipStream_t stream) {
    const float* x   = (const float*)d_in[0];
    const int*   ei  = (const int*)d_in[1];
    const float* W1  = (const float*)d_in[2];
    const float* b1  = (const float*)d_in[3];
    const float* W2  = (const float*)d_in[4];
    const float* b2  = (const float*)d_in[5];
    const float* Wmu = (const float*)d_in[6];
    const float* bmu = (const float*)d_in[7];
    const float* Wls = (const float*)d_in[8];
    const float* bls = (const float*)d_in[9];
    float* out = (float*)d_out;

    const int N = NN, E = EE;
    const int* row = ei;
    const int* col = ei + E;

    // workspace carve-up (256B aligned)
    char* p = (char*)d_ws;
    auto alloc = [&](size_t bytes) -> char* {
        char* r = p;
        p += (bytes + 255) & ~(size_t)255;
        return r;
    };
    int*   deg    = (int*)alloc((size_t)N * 4);
    int*   off    = (int*)alloc((size_t)(N + 1) * 4);
    int*   bsum   = (int*)alloc((size_t)256 * 4);
    float* dis    = (float*)alloc((size_t)N * 4);
    float* dis2   = (float*)alloc((size_t)N * 4);
    unsigned int* wB = (unsigned int*)alloc((size_t)TUW * 4);
    float* bB     = (float*)alloc((size_t)NBF * 4);
    unsigned int* eTag = (unsigned int*)alloc((size_t)E * 4);
    unsigned int* rr   = (unsigned int*)alloc((size_t)E * 4);
    unsigned short* y0 = (unsigned short*)alloc((size_t)N * S1 * 2);  // split 64+8
    unsigned short* y1 = (unsigned short*)alloc((size_t)N * S1 * 2);
    unsigned short* y2 = (unsigned short*)alloc((size_t)N * S1 * 2);
    unsigned short* y3 = (unsigned short*)alloc((size_t)N * S1 * 2);
    unsigned short* u0 = (unsigned short*)alloc((size_t)N * S2P * 2);
    unsigned short* u1 = (unsigned short*)alloc((size_t)N * S2P * 2);
    unsigned short* u2 = (unsigned short*)alloc((size_t)N * S2P * 2);
    unsigned short* u3 = (unsigned short*)alloc((size_t)N * S2P * 2);
    unsigned short* yh = (unsigned short*)alloc((size_t)N * 32 * 2);

    const unsigned int* W1b = wB;
    const unsigned int* W2b = wB + NU1;
    const unsigned int* Whb = wB + NU1 + NU2;
    const float* bv1 = bB;          // 288 cols
    const float* bv2 = bB + 288;    // 192 cols

    const int B = 256;
    int gE = (E + B - 1) / B;
    int nb = (N + SB - 1) / SB;  // 196 scan blocks

    // --- graph preprocessing -> CSR by destination (+ weight repack to bf16)
    init_kernel<<<nb, B, 0, stream>>>(W1, b1, W2, b2, Wmu, Wls, wB, bB, deg);
    hist_kernel<<<gE, B, 0, stream>>>(row, col, deg, rr, E);
    reduce_kernel<<<nb, SB, 0, stream>>>(deg, bsum, N);
    block_scan_kernel<<<nb, SB, 0, stream>>>(deg, bsum, off, dis, dis2, N, nb);
    fill_kernel<<<3200, B, 0, stream>>>(col, rr, dis, off, eTag, E);

    // grids
    int gmm  = (N + 63) / 64;                     // 782 GEMM blocks
    int ga72 = (N * (S1 / 8) + B - 1) / B;        // TPN 9
    int ga48 = (N * (S2P / 8) + B - 1) / B;       // TPN 6
    int gaF  = (N * 4 + B - 1) / B;               // TPN 4

    // --- TAG layer 1 via Horner: o1 = relu(y0 + A(y1 + A(y2 + A*y3)))
    // Split layout (64 main + 8 tail) for line-aligned gathers.
    gemm_kernel<3, 18, CIN, S1, true, true, false, true><<<gmm, B, 0, stream>>>(
        x, W1b, bv1, y0, y1, y2, y3, N);
    aggw_kernel<S1, true, false, true><<<ga72, B, 0, stream>>>(y3, y2, y2, off, eTag, N);
    aggw_kernel<S1, true, false, true><<<ga72, B, 0, stream>>>(y2, y1, y1, off, eTag, N);
    aggw_kernel<S1, true, true , true><<<ga72, B, 0, stream>>>(y1, y0, y0, off, eTag, N);
    // o1 = y0 (bf16, split layout, pad cols zero)

    // --- TAG layer 2 via Horner: o2 = relu(u0 + A(u1 + A(u2 + A*u3)))
    gemm_kernel<3, 12, S1, S2P, false, true, true, false><<<gmm, B, 0, stream>>>(
        y0, W2b, bv2, u0, u1, u2, u3, N);
    aggw_kernel<S2P, true, false, false><<<ga48, B, 0, stream>>>(u3, u2, u2, off, eTag, N);
    aggw_kernel<S2P, true, false, false><<<ga48, B, 0, stream>>>(u2, u1, u1, off, eTag, N);
    aggw_kernel<S2P, true, true , false><<<ga48, B, 0, stream>>>(u1, u0, u0, off, eTag, N);
    // o2 = u0 (bf16, stride S2P, pad cols zero)

    // --- GCN heads: MFMA head matmul (48 -> 32), then fused final agg
    gemm_kernel<2, 2, S2P, 32, false, false, false, false><<<gmm, B, 0, stream>>>(
        u0, Whb, nullptr, yh, yh, yh, yh, N);
    agg_gcn_final_kernel<<<gaF, B, 0, stream>>>(yh, off, eTag, dis2, bmu, bls, out, N);
}